// Round 8
// baseline (1155.792 us; speedup 1.0000x reference)
//
#include <hip/hip_runtime.h>
#include <hip/hip_bf16.h>

using u16 = unsigned short;
typedef __bf16 bf16x8_t __attribute__((ext_vector_type(8)));
typedef float    f32x4  __attribute__((ext_vector_type(4)));
typedef unsigned short u16x8 __attribute__((ext_vector_type(8)));

#define B_  64
#define L_  1024
#define TOT 65536
#define D_  512
#define H_  2048
#define NH_ 8
#define NC_ 8   // l-chunks of 128 tokens for fused attention pass

__device__ __forceinline__ float b2f(u16 x) {
    union { unsigned int i; float f; } v; v.i = ((unsigned int)x) << 16; return v.f;
}
__device__ __forceinline__ u16 f2b(float f) {
    union { float f; unsigned int i; } v; v.f = f;
    unsigned int i = v.i;
    unsigned int r = i + 0x7FFFu + ((i >> 16) & 1u);   // RNE
    return (u16)(r >> 16);
}

// ---------------- transpose + fp32->bf16 convert:  in[R][C] f32 -> out[C][R] bf16
__global__ __launch_bounds__(256) void transpose_cvt(const float* __restrict__ in,
                                                     u16* __restrict__ out, int R, int C) {
    __shared__ float tile[32][33];
    int c0 = blockIdx.x * 32, r0 = blockIdx.y * 32;
    int tx = threadIdx.x, ty = threadIdx.y;
    #pragma unroll
    for (int i = 0; i < 4; ++i)
        tile[ty + 8 * i][tx] = in[(size_t)(r0 + ty + 8 * i) * C + c0 + tx];
    __syncthreads();
    #pragma unroll
    for (int i = 0; i < 4; ++i)
        out[(size_t)(c0 + ty + 8 * i) * R + r0 + tx] = f2b(tile[tx][ty + 8 * i]);
}

// ---------------- straight fp32->bf16 convert (8 elems/thread)
__global__ __launch_bounds__(256) void cvt8_kernel(const float* __restrict__ in,
                                                   u16* __restrict__ out) {
    int i = (blockIdx.x * 256 + threadIdx.x) * 8;
    float4 a = *(const float4*)(in + i), b = *(const float4*)(in + i + 4);
    u16x8 o;
    o[0] = f2b(a.x); o[1] = f2b(a.y); o[2] = f2b(a.z); o[3] = f2b(a.w);
    o[4] = f2b(b.x); o[5] = f2b(b.y); o[6] = f2b(b.z); o[7] = f2b(b.w);
    *(u16x8*)(out + i) = o;
}

// ---------------- fused weight folding: qp -> wke -> wv2t/ck2 (+cvv on blocks 1,2)
// Each of 64 blocks recomputes qp and wke (cheap, ~0.5 MFLOP) into LDS, then
// emits its 32-row slice of wv2t. Kills the 5-kernel serial setup chain.
__global__ __launch_bounds__(256) void wv2f_kernel(const float* __restrict__ q,
                                                   const float* __restrict__ Wq,
                                                   const float* __restrict__ bq,
                                                   const float* __restrict__ Wk,
                                                   const float* __restrict__ bk,
                                                   const float* __restrict__ W2,
                                                   const float* __restrict__ b2,
                                                   const float* __restrict__ Wv,
                                                   const float* __restrict__ bv,
                                                   u16* __restrict__ wv2t,
                                                   float* __restrict__ ck2,
                                                   float* __restrict__ cvv) {
    __shared__ float qs[512];        // qp
    __shared__ float wk[512 * 8];    // wke
    const int tid = threadIdx.x;
    #pragma unroll
    for (int rep = 0; rep < 2; ++rep) {
        int j = rep * 256 + tid;
        float acc = bq[j];
        for (int d = 0; d < 512; ++d) acc += q[d] * Wq[(size_t)d * 512 + j];
        qs[j] = acc;
    }
    __syncthreads();
    for (int rep = 0; rep < 16; ++rep) {
        int d = rep * 32 + (tid >> 3);
        int h = tid & 7;
        float s = 0.f;
        const float* wr = Wk + (size_t)d * 512 + h * 64;
        const float* qr = qs + h * 64;
        for (int j = 0; j < 64; ++j) s += wr[j] * qr[j];
        wk[d * 8 + h] = 0.125f * s;
    }
    __syncthreads();
    {
        int k = blockIdx.x * 32 + (tid >> 3);
        int h = tid & 7;
        float s = 0.f;
        const float* row = W2 + (size_t)k * 512;
        for (int d = 0; d < 512; ++d) s += row[d] * wk[d * 8 + h];
        wv2t[(size_t)h * 2048 + k] = f2b(s);
        wv2t[(size_t)(h + 8) * 2048 + k] = 0;
    }
    if (blockIdx.x == 0 && tid < 8) {
        float c = 0.f;
        for (int j = 0; j < 64; ++j) c += bk[tid * 64 + j] * qs[tid * 64 + j];
        float c2 = 0.f;
        for (int d = 0; d < 512; ++d) c2 += b2[d] * wk[d * 8 + tid];
        ck2[tid] = c2 + 0.125f * c;
    }
    if (blockIdx.x == 1 || blockIdx.x == 2) {
        int e = (blockIdx.x - 1) * 256 + tid;
        float sv = bv[e];
        for (int d = 0; d < 512; ++d) sv += b2[d] * Wv[(size_t)d * 512 + e];
        cvv[e] = sv;
    }
}

// ---------------- gather emb rows -> bf16 z
__global__ __launch_bounds__(256) void embed_kernel(const int* __restrict__ idx,
                                                    const float* __restrict__ emb,
                                                    u16* __restrict__ z) {
    int u = blockIdx.x * 256 + threadIdx.x;   // one unit = 8 elements
    int t = u >> 6;
    int d0 = (u & 63) * 8;
    int row = idx[t];
    const float4* src = (const float4*)(emb + (size_t)row * 512 + d0);
    float4 a = src[0], b = src[1];
    u16x8 o;
    o[0] = f2b(a.x); o[1] = f2b(a.y); o[2] = f2b(a.z); o[3] = f2b(a.w);
    o[4] = f2b(b.x); o[5] = f2b(b.y); o[6] = f2b(b.z); o[7] = f2b(b.w);
    *(u16x8*)(z + (size_t)t * 512 + d0) = o;
}

// ---------------- bf16 GEMM 128x128, BK=64 (4 waves):  C = act(A@Bt^T [+ bias])
template <int RELU, int LNT, int BIAS>
__global__ __launch_bounds__(256) void gemm_bt(const u16* __restrict__ A,
                                               const u16* __restrict__ Bt,
                                               const float* __restrict__ bias,
                                               u16* __restrict__ C,
                                               int N, int K) {
    __shared__ __align__(16) u16 As[128 * 64];
    __shared__ __align__(16) u16 Bs[128 * 64];
    const int tid = threadIdx.x;
    const int id = blockIdx.x;
    const int xcd = id & 7, s = id >> 3;
    const int n_idx = s & ((1 << LNT) - 1);
    const int m_idx = xcd + 8 * (s >> LNT);
    const int m0 = m_idx * 128, n0 = n_idx * 128;
    const int lane = tid & 63, quad = lane >> 4, l15 = lane & 15;
    const int wave = tid >> 6, wm = wave >> 1, wn = wave & 1;

    f32x4 acc[4][4] = {};

    const int nK = K >> 6;
    for (int kt = 0; kt < nK; ++kt) {
        __syncthreads();
        const int kb = kt * 64;
        #pragma unroll
        for (int r = 0; r < 4; ++r) {
            int u = tid + r * 256;
            int row = u >> 3;
            int cg = (u & 7) ^ (row & 7);
            const u16* ga = A + (size_t)(m0 + row) * K + kb + cg * 8;
            __builtin_amdgcn_global_load_lds((const __attribute__((address_space(1))) void*)ga,
                                             (__attribute__((address_space(3))) void*)(&As[u * 8]),
                                             16, 0, 0);
            const u16* gb = Bt + (size_t)(n0 + row) * K + kb + cg * 8;
            __builtin_amdgcn_global_load_lds((const __attribute__((address_space(1))) void*)gb,
                                             (__attribute__((address_space(3))) void*)(&Bs[u * 8]),
                                             16, 0, 0);
        }
        __syncthreads();
        #pragma unroll
        for (int ks = 0; ks < 2; ++ks) {
            bf16x8_t af[4], bfr[4];
            #pragma unroll
            for (int mt = 0; mt < 4; ++mt) {
                int row = wm * 64 + mt * 16 + l15;
                int g = (ks * 4 + quad) ^ (row & 7);
                af[mt] = *(const bf16x8_t*)&As[row * 64 + g * 8];
            }
            #pragma unroll
            for (int nt = 0; nt < 4; ++nt) {
                int row = wn * 64 + nt * 16 + l15;
                int g = (ks * 4 + quad) ^ (row & 7);
                bfr[nt] = *(const bf16x8_t*)&Bs[row * 64 + g * 8];
            }
            #pragma unroll
            for (int mt = 0; mt < 4; ++mt)
                #pragma unroll
                for (int nt = 0; nt < 4; ++nt)
                    acc[mt][nt] = __builtin_amdgcn_mfma_f32_16x16x32_bf16(af[mt], bfr[nt],
                                                                          acc[mt][nt], 0, 0, 0);
        }
    }

    float bvv[4];
    #pragma unroll
    for (int nt = 0; nt < 4; ++nt)
        bvv[nt] = BIAS ? bias[n0 + wn * 64 + nt * 16 + l15] : 0.f;
    #pragma unroll
    for (int mt = 0; mt < 4; ++mt)
        #pragma unroll
        for (int nt = 0; nt < 4; ++nt)
            #pragma unroll
            for (int r = 0; r < 4; ++r) {
                int row = m0 + wm * 64 + mt * 16 + quad * 4 + r;
                int col = n0 + wn * 64 + nt * 16 + l15;
                float v = acc[mt][nt][r] + bvv[nt];
                if (RELU) v = fmaxf(v, 0.f);
                C[(size_t)row * N + col] = f2b(v);
            }
}

// ---------------- bf16 GEMM 256x128, BK=64, 8 waves: C = relu(A@Bt^T + bias)
template <int RELU, int LNT>
__global__ __launch_bounds__(512) void gemm_bt256(const u16* __restrict__ A,
                                                  const u16* __restrict__ Bt,
                                                  const float* __restrict__ bias,
                                                  u16* __restrict__ C,
                                                  int N, int K) {
    __shared__ __align__(16) u16 As[256 * 64];
    __shared__ __align__(16) u16 Bs[128 * 64];
    const int tid = threadIdx.x;
    const int id = blockIdx.x;
    const int xcd = id & 7, s = id >> 3;
    const int n_idx = s & ((1 << LNT) - 1);
    const int m_idx = xcd + 8 * (s >> LNT);
    const int m0 = m_idx * 256, n0 = n_idx * 128;
    const int lane = tid & 63, quad = lane >> 4, l15 = lane & 15;
    const int wave = tid >> 6, wm = wave >> 1, wn = wave & 1;

    f32x4 acc[4][4] = {};

    const int nK = K >> 6;
    for (int kt = 0; kt < nK; ++kt) {
        __syncthreads();
        const int kb = kt * 64;
        #pragma unroll
        for (int r = 0; r < 4; ++r) {
            int u = tid + r * 512;
            int row = u >> 3;
            int cg = (u & 7) ^ (row & 7);
            const u16* ga = A + (size_t)(m0 + row) * K + kb + cg * 8;
            __builtin_amdgcn_global_load_lds((const __attribute__((address_space(1))) void*)ga,
                                             (__attribute__((address_space(3))) void*)(&As[u * 8]),
                                             16, 0, 0);
        }
        #pragma unroll
        for (int r = 0; r < 2; ++r) {
            int u = tid + r * 512;
            int row = u >> 3;
            int cg = (u & 7) ^ (row & 7);
            const u16* gb = Bt + (size_t)(n0 + row) * K + kb + cg * 8;
            __builtin_amdgcn_global_load_lds((const __attribute__((address_space(1))) void*)gb,
                                             (__attribute__((address_space(3))) void*)(&Bs[u * 8]),
                                             16, 0, 0);
        }
        __syncthreads();
        #pragma unroll
        for (int ks = 0; ks < 2; ++ks) {
            bf16x8_t af[4], bfr[4];
            #pragma unroll
            for (int mt = 0; mt < 4; ++mt) {
                int row = wm * 64 + mt * 16 + l15;
                int g = (ks * 4 + quad) ^ (row & 7);
                af[mt] = *(const bf16x8_t*)&As[row * 64 + g * 8];
            }
            #pragma unroll
            for (int nt = 0; nt < 4; ++nt) {
                int row = wn * 64 + nt * 16 + l15;
                int g = (ks * 4 + quad) ^ (row & 7);
                bfr[nt] = *(const bf16x8_t*)&Bs[row * 64 + g * 8];
            }
            #pragma unroll
            for (int mt = 0; mt < 4; ++mt)
                #pragma unroll
                for (int nt = 0; nt < 4; ++nt)
                    acc[mt][nt] = __builtin_amdgcn_mfma_f32_16x16x32_bf16(af[mt], bfr[nt],
                                                                          acc[mt][nt], 0, 0, 0);
        }
    }

    float bvv[4];
    #pragma unroll
    for (int nt = 0; nt < 4; ++nt) bvv[nt] = bias[n0 + wn * 64 + nt * 16 + l15];
    #pragma unroll
    for (int mt = 0; mt < 4; ++mt)
        #pragma unroll
        for (int nt = 0; nt < 4; ++nt)
            #pragma unroll
            for (int r = 0; r < 4; ++r) {
                int row = m0 + wm * 64 + mt * 16 + quad * 4 + r;
                int col = n0 + wn * 64 + nt * 16 + l15;
                float v = acc[mt][nt][r] + bvv[nt];
                if (RELU) v = fmaxf(v, 0.f);
                C[(size_t)row * N + col] = f2b(v);
            }
}

// ---------------- fused flash-style attention pool over 128-token chunks.
__global__ __launch_bounds__(256) void attn2_kernel(const u16* __restrict__ C1,
                                                    const u16* __restrict__ wv2t,
                                                    const float* __restrict__ ck2,
                                                    float* __restrict__ pbuf,
                                                    float* __restrict__ msbuf) {
    __shared__ __align__(16) u16 bsh[16 * 2048];   // 64 KB
    __shared__ float sc[128][8];                   // raw scores
    __shared__ float pp[128][8];                   // exp(s - m_c)
    __shared__ float mh[8];
    const int c = blockIdx.x, b = blockIdx.y, tid = threadIdx.x;
    const int w = tid >> 6, lane = tid & 63, quad = lane >> 4, l15 = lane & 15;

    for (int i = tid; i < 4096; i += 256)
        ((float4*)bsh)[i] = ((const float4*)wv2t)[i];
    __syncthreads();

    const int t0 = b * 1024 + c * 128;
    // --- phase 1: wave w scores tokens t0 + w*32 .. +31 (two 16-token MFMA tiles)
    #pragma unroll
    for (int mt2 = 0; mt2 < 2; ++mt2) {
        const u16* arow = C1 + (size_t)(t0 + w * 32 + mt2 * 16 + l15) * 2048 + quad * 8;
        const u16* brow = &bsh[l15 * 2048 + quad * 8];
        f32x4 acc = {};
        #pragma unroll 4
        for (int kt = 0; kt < 64; ++kt) {
            bf16x8_t af = *(const bf16x8_t*)(arow + kt * 32);
            bf16x8_t bf = *(const bf16x8_t*)(brow + kt * 32);
            acc = __builtin_amdgcn_mfma_f32_16x16x32_bf16(af, bf, acc, 0, 0, 0);
        }
        if (l15 < 8) {
            float ck = ck2[l15];
            #pragma unroll
            for (int r = 0; r < 4; ++r)
                sc[w * 32 + mt2 * 16 + quad * 4 + r][l15] = acc[r] + ck;
        }
    }
    __syncthreads();
    if (tid < 8) {
        float m = -1e30f;
        for (int l = 0; l < 128; ++l) m = fmaxf(m, sc[l][tid]);
        mh[tid] = m;
    }
    __syncthreads();
    for (int i = tid; i < 1024; i += 256) {
        int l = i >> 3, h = i & 7;
        pp[l][h] = __expf(sc[l][h] - mh[h]);
    }
    __syncthreads();
    if (tid < 8) {
        float s = 0.f;
        for (int l = 0; l < 128; ++l) s += pp[l][tid];
        float* mb = msbuf + ((size_t)b * NC_ + c) * 16;
        mb[tid] = mh[tid];
        mb[8 + tid] = s;
    }
    // --- phase 2: wave w owns cols [w*512, w*512+512); lane owns 8 cols (L2-hot)
    const u16* crow = C1 + (size_t)t0 * 2048 + w * 512 + lane * 8;
    float acc2[8][8] = {};
    for (int l = 0; l < 128; ++l) {
        u16x8 v = *(const u16x8*)(crow + (size_t)l * 2048);
        float av[8];
        #pragma unroll
        for (int hh = 0; hh < 8; ++hh) av[hh] = pp[l][hh];
        #pragma unroll
        for (int j = 0; j < 8; ++j) {
            float hf = b2f(v[j]);
            #pragma unroll
            for (int hh = 0; hh < 8; ++hh) acc2[hh][j] += av[hh] * hf;
        }
    }
    float* pw = pbuf + (((size_t)b * NC_ + c) * 8) * 2048 + w * 512 + lane * 8;
    #pragma unroll
    for (int hh = 0; hh < 8; ++hh) {
        float4 lo, hi;
        lo.x = acc2[hh][0]; lo.y = acc2[hh][1]; lo.z = acc2[hh][2]; lo.w = acc2[hh][3];
        hi.x = acc2[hh][4]; hi.y = acc2[hh][5]; hi.z = acc2[hh][6]; hi.w = acc2[hh][7];
        *(float4*)(pw + (size_t)hh * 2048) = lo;
        *(float4*)(pw + (size_t)hh * 2048 + 4) = hi;
    }
}

// ---------------- fused tail per set: flash fold -> ctx(WWb)+cvv -> pooled(Wo)+LN
// -> h1(Wh1) -> h2(Wh2) -> out[b]
__global__ __launch_bounds__(256) void head_kernel(const float* __restrict__ pbuf,
                                                   const float* __restrict__ msbuf,
                                                   const u16* __restrict__ WWb,
                                                   const float* __restrict__ cvv,
                                                   const float* __restrict__ Wo,
                                                   const float* __restrict__ bo,
                                                   const float* __restrict__ g,
                                                   const float* __restrict__ lb,
                                                   const float* __restrict__ Wh1,
                                                   const float* __restrict__ bh1,
                                                   const float* __restrict__ Wh2,
                                                   const float* __restrict__ bh2,
                                                   float* __restrict__ out) {
    __shared__ float g1c[8 * 2048];   // 64 KB
    __shared__ float ctx[512];
    __shared__ float yv[512];
    __shared__ float scl[NC_ * 8];
    __shared__ float red[8];
    __shared__ float stats[2];
    const int b = blockIdx.x, tid = threadIdx.x;
    if (tid < 8) {
        const float* mb = msbuf + (size_t)b * NC_ * 16;
        float m = -1e30f;
        for (int c = 0; c < NC_; ++c) m = fmaxf(m, mb[c * 16 + tid]);
        float den = 0.f;
        for (int c = 0; c < NC_; ++c) den += mb[c * 16 + 8 + tid] * __expf(mb[c * 16 + tid] - m);
        float inv = 1.f / den;
        for (int c = 0; c < NC_; ++c) scl[c * 8 + tid] = __expf(mb[c * 16 + tid] - m) * inv;
    }
    __syncthreads();
    for (int i = tid; i < 16384; i += 256) {
        int hh = i >> 11, k = i & 2047;
        float s = 0.f;
        #pragma unroll
        for (int c = 0; c < NC_; ++c)
            s += pbuf[(((size_t)b * NC_ + c) * 8 + hh) * 2048 + k] * scl[c * 8 + hh];
        g1c[hh * 2048 + k] = s;
    }
    __syncthreads();
    // ctx[e] = cvv[e] + sum_k g1[h(e)][k] * WW[k][e]
    #pragma unroll
    for (int rep = 0; rep < 2; ++rep) {
        int e = rep * 256 + tid;
        int hh = e >> 6;
        const float* gr = &g1c[hh * 2048];
        float s = cvv[e];
        for (int k = 0; k < 2048; ++k) s += gr[k] * b2f(WWb[(size_t)k * 512 + e]);
        ctx[e] = s;
    }
    __syncthreads();
    // pooled = ctx @ Wo + bo; LN
    float pv[2]; float psum = 0.f, psq = 0.f;
    #pragma unroll
    for (int ph = 0; ph < 2; ++ph) {
        int e2 = tid + ph * 256;
        float acc = bo[e2];
        for (int ee = 0; ee < 512; ++ee) acc += ctx[ee] * Wo[(size_t)ee * 512 + e2];
        pv[ph] = acc; psum += acc; psq += acc * acc;
    }
    for (int off = 32; off; off >>= 1) { psum += __shfl_xor(psum, off, 64); psq += __shfl_xor(psq, off, 64); }
    const int w = tid >> 6, lane = tid & 63;
    if (lane == 0) { red[w] = psum; red[4 + w] = psq; }
    __syncthreads();
    if (tid == 0) {
        float s = red[0] + red[1] + red[2] + red[3];
        float q2 = red[4] + red[5] + red[6] + red[7];
        float mu = s / 512.f;
        float var = q2 / 512.f - mu * mu;
        stats[0] = mu; stats[1] = 1.f / sqrtf(var + 1e-5f);
    }
    __syncthreads();
    #pragma unroll
    for (int ph = 0; ph < 2; ++ph) {
        int e2 = tid + ph * 256;
        yv[e2] = (pv[ph] - stats[0]) * stats[1] * g[e2] + lb[e2];
    }
    __syncthreads();
    // h1 + h2 fused: hsum = sum_j relu(y@Wh1 + bh1)[j] * Wh2[j]
    float hsum = 0.f;
    for (int j = tid; j < 2048; j += 256) {
        float acc = bh1[j];
        for (int d = 0; d < 512; ++d) acc += yv[d] * Wh1[(size_t)d * 2048 + j];
        hsum += fmaxf(acc, 0.f) * Wh2[j];
    }
    for (int off = 32; off; off >>= 1) hsum += __shfl_xor(hsum, off, 64);
    if (lane == 0) red[w] = hsum;
    __syncthreads();
    if (tid == 0) out[b] = red[0] + red[1] + red[2] + red[3] + bh2[0];
}

extern "C" void kernel_launch(void* const* d_in, const int* in_sizes, int n_in,
                              void* d_out, int out_size, void* d_ws, size_t ws_size,
                              hipStream_t stream) {
    const int*   mut_idx = (const int*)d_in[0];
    const float* emb  = (const float*)d_in[2];
    const float* W1   = (const float*)d_in[3];
    const float* b1   = (const float*)d_in[4];
    const float* W2   = (const float*)d_in[5];
    const float* b2   = (const float*)d_in[6];
    const float* q    = (const float*)d_in[7];
    const float* Wq   = (const float*)d_in[8];
    const float* bq   = (const float*)d_in[9];
    const float* Wk   = (const float*)d_in[10];
    const float* bk   = (const float*)d_in[11];
    const float* Wv   = (const float*)d_in[12];
    const float* bv   = (const float*)d_in[13];
    const float* Wo   = (const float*)d_in[14];
    const float* bo   = (const float*)d_in[15];
    const float* ln_g = (const float*)d_in[16];
    const float* ln_b = (const float*)d_in[17];
    const float* Wh1  = (const float*)d_in[18];
    const float* bh1  = (const float*)d_in[19];
    const float* Wh2  = (const float*)d_in[20];
    const float* bh2  = (const float*)d_in[21];
    float* out = (float*)d_out;

    // workspace layout (256B aligned)
    char* p = (char*)d_ws;
    auto alloc = [&](size_t bytes) {
        char* r = p; p += (bytes + 255) & ~(size_t)255; return r;
    };
    u16*  W1t  = (u16*)alloc((size_t)H_ * D_ * 2);              // 2 MB
    u16*  W2b  = (u16*)alloc((size_t)H_ * D_ * 2);              // 2 MB
    u16*  Wvt  = (u16*)alloc((size_t)D_ * D_ * 2);              // 512 KB
    u16*  WWb  = (u16*)alloc((size_t)H_ * D_ * 2);              // 2 MB
    u16*  wv2t = (u16*)alloc((size_t)16 * H_ * 2);              // 64 KB
    float* ck2 = (float*)alloc(NH_ * 4);
    float* cvv = (float*)alloc(D_ * 4);
    float* msbuf = (float*)alloc((size_t)B_ * NC_ * 16 * 4);    // 32 KB
    float* pbuf = (float*)alloc((size_t)B_ * NC_ * NH_ * H_ * 4); // 33.5 MB
    u16*  z    = (u16*)alloc((size_t)TOT * D_ * 2);             // 67 MB
    u16*  C1   = (u16*)alloc((size_t)TOT * H_ * 2);             // 268 MB

    // setup / weight folding (bf16 MFMA for WW = W2 @ Wv)
    transpose_cvt<<<dim3(H_ / 32, D_ / 32), dim3(32, 8), 0, stream>>>(W1, W1t, D_, H_);
    transpose_cvt<<<dim3(D_ / 32, D_ / 32), dim3(32, 8), 0, stream>>>(Wv, Wvt, D_, D_);
    cvt8_kernel<<<(H_ * D_ / 8) / 256, 256, 0, stream>>>(W2, W2b);
    wv2f_kernel<<<64, 256, 0, stream>>>(q, Wq, bq, Wk, bk, W2, b2, Wv, bv, wv2t, ck2, cvv);
    gemm_bt<0, 2, 0><<<dim3((H_ / 128) * 4), 256, 0, stream>>>(W2b, Wvt, nullptr, WWb, D_, D_);

    // phi layer-1 only (layer-2 algebraically folded away)
    embed_kernel<<<TOT / 4, 256, 0, stream>>>(mut_idx, emb, z);
    gemm_bt256<1, 4><<<dim3((TOT / 256) * 16), 512, 0, stream>>>(z, W1t, b1, C1, H_, D_);

    // fused flash-style attention pool on C1 + fully-fused tail
    attn2_kernel<<<dim3(NC_, B_), 256, 0, stream>>>(C1, wv2t, ck2, pbuf, msbuf);
    head_kernel<<<B_, 256, 0, stream>>>(pbuf, msbuf, WWb, cvv, Wo, bo, ln_g, ln_b,
                                        Wh1, bh1, Wh2, bh2, out);
}